// Round 13
// baseline (238.879 us; speedup 1.0000x reference)
//
#include <hip/hip_runtime.h>
#include <hip/hip_bf16.h>

typedef __attribute__((ext_vector_type(4))) short shortx4;
typedef __attribute__((ext_vector_type(8))) short short8;
typedef __attribute__((ext_vector_type(4))) float floatx4;

__device__ __forceinline__ unsigned short f2bf(float f) {
    __hip_bfloat16 h = __float2bfloat16(f);
    return __builtin_bit_cast(unsigned short, h);
}

#define GLOAD_LDS16(g, l) __builtin_amdgcn_global_load_lds(                      \
    (const __attribute__((address_space(1))) void*)(g),                          \
    (__attribute__((address_space(3))) void*)(l), 16, 0, 0)

// =============== sweep: single NT read of input; emits
//   - bf16 copy as 128x128 grid of 8x8-entry tiles (4096 shorts each, swizzled)
//   - rowpart[ti][c][k], colpart[tj][r][k] partials
//   - diagbuf rows (on diagonal tiles)
// grid (tj=64, ti=64), 256 thr; block = one 16x16 entry region
__global__ __launch_bounds__(256) void sweep_kernel(const float* __restrict__ in,
        unsigned short* __restrict__ bfcopy, float* __restrict__ rowpart,
        float* __restrict__ colpart, float* __restrict__ diagbuf) {
    __shared__ float colp[4][16][64];
    int t = threadIdx.x;
    int kq = t & 15;              // k-granule (4 floats)
    int cl = (t >> 4) & 3;
    int w  = t >> 6;
    int c  = w * 4 + cl;          // local col 0..15
    int ti = blockIdx.y, tj = blockIdx.x;
    int R = ti * 16, C = tj * 16;
    const float* base = in + ((size_t)R << 16) + (size_t)(C + c) * 64 + kq * 4;
    bool dt = (ti == tj);

    floatx4 rowacc = (floatx4){0.f, 0.f, 0.f, 0.f};
    #pragma unroll
    for (int i = 0; i < 16; ++i) {
        floatx4 v = __builtin_nontemporal_load((const floatx4*)(base + ((size_t)i << 16)));
        rowacc += v;
        // bf16 copy: 8x8-entry tile (bi8,bj8), row64 = (i&7)*8 + (c&7)
        int row64 = (i & 7) * 8 + (c & 7);
        int tid8 = (ti * 2 + (i >> 3)) * 128 + (tj * 2 + (c >> 3));
        int wg = (kq >> 1) ^ (row64 & 7) ^ ((row64 >> 3) & 7);
        shortx4 h;
        h[0] = (short)f2bf(v[0]); h[1] = (short)f2bf(v[1]);
        h[2] = (short)f2bf(v[2]); h[3] = (short)f2bf(v[3]);
        *(shortx4*)(bfcopy + ((size_t)tid8 << 12) + row64 * 64 + wg * 8 + (kq & 1) * 4) = h;
        if (dt && c == i)
            *(floatx4*)&diagbuf[(size_t)(R + i) * 64 + kq * 4] = v;
        // column-direction: reduce over the 4 cl's in-wave
        floatx4 cs = v;
        #pragma unroll
        for (int m = 16; m <= 32; m <<= 1) {
            cs[0] += __shfl_xor(cs[0], m);
            cs[1] += __shfl_xor(cs[1], m);
            cs[2] += __shfl_xor(cs[2], m);
            cs[3] += __shfl_xor(cs[3], m);
        }
        if (cl == 0) *(floatx4*)&colp[w][i][kq * 4] = cs;
    }
    *(floatx4*)&rowpart[(size_t)ti * 65536 + (size_t)(C + c) * 64 + kq * 4] = rowacc;
    __syncthreads();
    int i2 = t >> 4, kq2 = t & 15;
    floatx4 s = *(const floatx4*)&colp[0][i2][kq2 * 4];
    s += *(const floatx4*)&colp[1][i2][kq2 * 4];
    s += *(const floatx4*)&colp[2][i2][kq2 * 4];
    s += *(const floatx4*)&colp[3][i2][kq2 * 4];
    *(floatx4*)&colpart[(size_t)tj * 65536 + (size_t)(R + i2) * 64 + kq2 * 4] = s;
}

// =============== poolfin: block-specialized finisher
__global__ __launch_bounds__(256) void poolfin_kernel(const float* __restrict__ rowpart,
        const float* __restrict__ colpart, const float* __restrict__ diagbuf,
        const float* __restrict__ wts,
        float* __restrict__ row_pool, float* __restrict__ col_pool,
        float* __restrict__ allraw, float* __restrict__ diagraw,
        unsigned short* __restrict__ w0t, unsigned short* __restrict__ w1t) {
    __shared__ float red[16][64];
    int b = blockIdx.x, t = threadIdx.x;
    if (b < 64) {                           // row_pool
        int j = b * 256 + t;
        const floatx4* rp4 = (const floatx4*)rowpart;
        floatx4 s = (floatx4){0.f, 0.f, 0.f, 0.f};
        #pragma unroll 8
        for (int y = 0; y < 64; ++y) s += rp4[(size_t)y * 16384 + j];
        *(floatx4*)&row_pool[j * 4] = s * (1.f / 1024.f);
    } else if (b < 128) {                   // col_pool + allraw
        int j = (b - 64) * 256 + t;
        const floatx4* cp4 = (const floatx4*)colpart;
        floatx4 s = (floatx4){0.f, 0.f, 0.f, 0.f};
        #pragma unroll 8
        for (int y = 0; y < 64; ++y) s += cp4[(size_t)y * 16384 + j];
        *(floatx4*)&col_pool[j * 4] = s * (1.f / 1024.f);
        *(floatx4*)&red[t >> 4][(t & 15) * 4] = s;
        __syncthreads();
        if (t < 64) {
            float a = 0.f;
            #pragma unroll
            for (int q = 0; q < 16; ++q) a += red[q][t];
            atomicAdd(&allraw[t], a);
        }
    } else if (b < 136) {                   // diag sum (8 blocks x 128 rows)
        int d = b - 128;
        int k = t & 63, rl = t >> 6;
        float sd = 0.f;
        #pragma unroll 8
        for (int u = 0; u < 32; ++u)
            sd += diagbuf[(size_t)(d * 128 + rl + 4 * u) * 64 + k];
        red[rl][k] = sd;
        __syncthreads();
        if (t < 64)
            atomicAdd(&diagraw[t], red[0][t] + red[1][t] + red[2][t] + red[3][t]);
    } else {                                // wconv (16 blocks)
        int idx = (b - 136) * 256 + t;
        int n = idx >> 6, k = idx & 63;
        w0t[idx] = f2bf(wts[k * 64 + n]);
        w1t[idx] = f2bf(wts[4096 + k * 64 + n]);
    }
}

// =============== abd: 128 blocks x 8 rows (W streamed once per block)
__global__ __launch_bounds__(256) void abd_kernel(const float* __restrict__ W,
        const float* __restrict__ col_pool, const float* __restrict__ row_pool,
        const float* __restrict__ diagbuf, const float* __restrict__ allraw,
        const float* __restrict__ diagraw,
        float* __restrict__ Ab, float* __restrict__ Bb, float* __restrict__ Dgb) {
    __shared__ float rp[8][64], cp[8][64], dv[8][64], ap[64], dp[64];
    int t = threadIdx.x, o = t & 63, il = t >> 6;
    int i0 = blockIdx.x * 8;
    #pragma unroll
    for (int q = 0; q < 2; ++q) {
        int ii = il + 4 * q;
        rp[ii][o] = row_pool[(i0 + ii) * 64 + o];
        cp[ii][o] = col_pool[(i0 + ii) * 64 + o];
        dv[ii][o] = diagbuf[(i0 + ii) * 64 + o];
    }
    if (t < 64) {
        ap[t] = allraw[t] * (1.f / 1048576.f);
        dp[t] = diagraw[t] * (1.f / 1024.f);
    }
    __syncthreads();
    int iA = il, iB = il + 4;
    float aA0 = 0.f, aA1 = 0.f, aB0 = 0.f, aB1 = 0.f, aD0 = 0.f, aD1 = 0.f;
    float cA = 0.f, cD = 0.f;
    #pragma unroll 4
    for (int k = 0; k < 64; ++k) {
        int ko = k * 64 + o;
        float w2  = W[2 * 4096 + ko],  w3  = W[3 * 4096 + ko];
        float w4  = W[4 * 4096 + ko],  w5  = W[5 * 4096 + ko];
        float w6  = W[6 * 4096 + ko],  w7  = W[7 * 4096 + ko];
        float w8  = W[8 * 4096 + ko],  w9  = W[9 * 4096 + ko];
        float w10 = W[10 * 4096 + ko], w11 = W[11 * 4096 + ko];
        float w12 = W[12 * 4096 + ko], w13 = W[13 * 4096 + ko];
        float w14 = W[14 * 4096 + ko];
        float rA = rp[iA][k], cAk = cp[iA][k], dA = dv[iA][k];
        float rB = rp[iB][k], cBk = cp[iB][k], dB = dv[iB][k];
        aA0 += rA * w3 + cAk * w6 + dA * w13;
        aA1 += rB * w3 + cBk * w6 + dB * w13;
        aB0 += rA * w4 + cAk * w5 + dA * w14;
        aB1 += rB * w4 + cBk * w5 + dB * w14;
        aD0 += dA * w2 + rA * w10 + cAk * w11;
        aD1 += dB * w2 + rB * w10 + cBk * w11;
        cA += ap[k] * w7 + dp[k] * w12;
        cD += dp[k] * w8 + ap[k] * w9;
    }
    Ab[(i0 + iA) * 64 + o]  = aA0 + cA;
    Ab[(i0 + iB) * 64 + o]  = aA1 + cA;
    Bb[(i0 + iA) * 64 + o]  = aB0;
    Bb[(i0 + iB) * 64 + o]  = aB1;
    Dgb[(i0 + iA) * 64 + o] = aD0 + cD;
    Dgb[(i0 + iB) * 64 + o] = aD1 + cD;
}

// =============== main paired-tile kernel: 8256 blocks x 256 thr, 16 KB LDS
// 8x8-entry pair tiles -> 4 blocks/CU. Stage = global_load_lds DMA; NT stores.
__global__ __launch_bounds__(256, 4) void main_kernel(const unsigned short* __restrict__ bfcopy,
        const unsigned short* __restrict__ w0t, const unsigned short* __restrict__ w1t,
        const float* __restrict__ Ab, const float* __restrict__ Bb,
        const float* __restrict__ Dgb, float* __restrict__ out) {
    __shared__ short lds[8192];           // 2 tiles * 4096 shorts (swizzled image)

    int t = threadIdx.x;
    int lane = t & 63, w = t >> 6;        // 4 waves; wave w owns fragment f = w
    int lrow = lane & 15, lhi = lane >> 4;

    // triangular decode over 128x128 tile grid
    int p = blockIdx.x;
    float fb = (257.0f - sqrtf(257.0f * 257.0f - 8.0f * (float)p)) * 0.5f;
    int bi = (int)fb;
    while (bi > 0 && bi * (257 - bi) / 2 > p) --bi;
    while ((bi + 1) * (257 - (bi + 1)) / 2 <= p) ++bi;
    int bj = bi + (p - bi * (257 - bi) / 2);
    int r0 = bi * 8, c0 = bj * 8;
    bool diag = (bi == bj);

    // stage: direct global->LDS DMA (16 B/lane, linear pre-swizzled image)
    const unsigned short* t0 = bfcopy + ((size_t)(bi * 128 + bj) << 12);
    const unsigned short* t1 = bfcopy + ((size_t)(bj * 128 + bi) << 12);
    #pragma unroll
    for (int n = 0; n < 2; ++n) {
        int g = n * 256 + t;
        GLOAD_LDS16(t0 + g * 8, lds + g * 8);
    }
    if (!diag) {
        #pragma unroll
        for (int n = 0; n < 2; ++n) {
            int g = n * 256 + t;
            GLOAD_LDS16(t1 + g * 8, lds + 4096 + g * 8);
        }
    }

    // W fragments (register-resident) — overlapped with the DMA
    short8 bw0[2][4], bw1[2][4];
    #pragma unroll
    for (int kg = 0; kg < 2; ++kg)
        #pragma unroll
        for (int nt = 0; nt < 4; ++nt) {
            int off = (nt * 16 + lrow) * 64 + kg * 32 + lhi * 8;
            bw0[kg][nt] = *(const short8*)(w0t + off);
            bw1[kg][nt] = *(const short8*)(w1t + off);
        }
    __syncthreads();

    int base1 = diag ? 0 : 4096;          // diagonal pair: tile1 == tile0

    // direct rows: mrow = w*16+lrow ; transposed rows: (lrow&7)*8 + w*2 + (lrow>>3)
    int mrow = w * 16 + lrow;
    int swzm = (mrow & 7) ^ ((mrow >> 3) & 7);
    int trow = (lrow & 7) * 8 + w * 2 + (lrow >> 3);
    int swzt = (trow & 7) ^ ((trow >> 3) & 7);

    #pragma unroll
    for (int sel = 0; sel < 2; ++sel) {
        if (sel == 1 && diag) continue;   // diagonal pair: both out-tiles identical
        int selb = sel ? base1 : 0;
        int othb = sel ? 0 : base1;
        int rbase = sel ? c0 : r0;
        int cbase = sel ? r0 : c0;

        short8 ad[2], at2[2];
        #pragma unroll
        for (int kg = 0; kg < 2; ++kg) {
            ad[kg]  = *(const short8*)(lds + selb + mrow * 64 + ((kg * 4 + lhi) ^ swzm) * 8);
            at2[kg] = *(const short8*)(lds + othb + trow * 64 + ((kg * 4 + lhi) ^ swzt) * 8);
        }
        floatx4 acc[4];
        #pragma unroll
        for (int nt = 0; nt < 4; ++nt) acc[nt] = (floatx4){0.f, 0.f, 0.f, 0.f};
        #pragma unroll
        for (int nt = 0; nt < 4; ++nt) {
            acc[nt] = __builtin_amdgcn_mfma_f32_16x16x32_bf16(ad[0],  bw0[0][nt], acc[nt], 0, 0, 0);
            acc[nt] = __builtin_amdgcn_mfma_f32_16x16x32_bf16(ad[1],  bw0[1][nt], acc[nt], 0, 0, 0);
            acc[nt] = __builtin_amdgcn_mfma_f32_16x16x32_bf16(at2[0], bw1[0][nt], acc[nt], 0, 0, 0);
            acc[nt] = __builtin_amdgcn_mfma_f32_16x16x32_bf16(at2[1], bw1[1][nt], acc[nt], 0, 0, 0);
        }
        #pragma unroll
        for (int jj = 0; jj < 4; ++jj) {
            int rl = w * 16 + lhi * 4 + jj;        // local D row 0..63
            int ridx = rbase + (rl >> 3);
            int cidx = cbase + (rl & 7);
            size_t s = ((size_t)ridx << 10) + cidx;
            bool isd = diag && ((rl >> 3) == (rl & 7));
            #pragma unroll
            for (int nt = 0; nt < 4; ++nt) {
                int n = nt * 16 + lrow;
                float v = acc[nt][jj] + Ab[cidx * 64 + n] + Bb[ridx * 64 + n];
                if (isd) v += Dgb[ridx * 64 + n];
                __builtin_nontemporal_store(v, &out[s * 64 + n]);
            }
        }
    }
}

extern "C" void kernel_launch(void* const* d_in, const int* in_sizes, int n_in,
                              void* d_out, int out_size, void* d_ws, size_t ws_size,
                              hipStream_t stream) {
    const float* in  = (const float*)d_in[0];
    const float* wts = (const float*)d_in[1];
    float* out = (float*)d_out;
    float* ws = (float*)d_ws;

    unsigned short* bfcopy = (unsigned short*)ws;       // 67108864 shorts = 128 MB
    float* rowpart  = ws + 33554432;         // 64*65536 = 4194304
    float* colpart  = ws + 37748736;         // 4194304
    float* row_pool = ws + 41943040;         // 65536
    float* col_pool = ws + 42008576;         // 65536
    float* diagbuf  = ws + 42074112;         // 65536
    float* allraw   = ws + 42139648;         // 64
    float* diagraw  = ws + 42139712;         // 64
    float* Ab       = ws + 42139776;         // 65536
    float* Bb       = ws + 42205312;         // 65536
    float* Dgb      = ws + 42270848;         // 65536
    unsigned short* w0t = (unsigned short*)(ws + 42336384);  // 4096 u16
    unsigned short* w1t = w0t + 4096;                        // 4096 u16

    (void)hipMemsetAsync((void*)allraw, 0, 128 * sizeof(float), stream);

    sweep_kernel<<<dim3(64, 64), 256, 0, stream>>>(in, bfcopy, rowpart, colpart, diagbuf);
    poolfin_kernel<<<152, 256, 0, stream>>>(rowpart, colpart, diagbuf, wts,
                                            row_pool, col_pool, allraw, diagraw, w0t, w1t);
    abd_kernel<<<128, 256, 0, stream>>>(wts, col_pool, row_pool, diagbuf,
                                        allraw, diagraw, Ab, Bb, Dgb);
    main_kernel<<<8256, 256, 0, stream>>>(bfcopy, w0t, w1t, Ab, Bb, Dgb, out);
}

// Round 14
// 221.265 us; speedup vs baseline: 1.0796x; 1.0796x over previous
//
#include <hip/hip_runtime.h>
#include <hip/hip_bf16.h>

typedef __attribute__((ext_vector_type(4))) short shortx4;
typedef __attribute__((ext_vector_type(8))) short short8;
typedef __attribute__((ext_vector_type(4))) float floatx4;

__device__ __forceinline__ unsigned short f2bf(float f) {
    __hip_bfloat16 h = __float2bfloat16(f);
    return __builtin_bit_cast(unsigned short, h);
}

#define GLOAD_LDS16(g, l) __builtin_amdgcn_global_load_lds(                      \
    (const __attribute__((address_space(1))) void*)(g),                          \
    (__attribute__((address_space(3))) void*)(l), 16, 0, 0)

// =============== sweep: single NT read of input (R12-exact) ===============
__global__ __launch_bounds__(256) void sweep_kernel(const float* __restrict__ in,
        unsigned short* __restrict__ bfcopy, float* __restrict__ rowpart,
        float* __restrict__ colpart, float* __restrict__ diagbuf) {
    __shared__ float colp[4][16][64];
    int t = threadIdx.x;
    int kq = t & 15;              // k-granule (4 floats)
    int cl = (t >> 4) & 3;
    int w  = t >> 6;
    int c  = w * 4 + cl;          // local col 0..15
    int ti = blockIdx.y, tj = blockIdx.x;
    int R = ti * 16, C = tj * 16;
    const float* base = in + ((size_t)R << 16) + (size_t)(C + c) * 64 + kq * 4;
    unsigned short* tbase = bfcopy + ((size_t)(ti * 64 + tj) << 14);   // 16384 shorts/tile
    bool dt = (ti == tj);

    floatx4 rowacc = (floatx4){0.f, 0.f, 0.f, 0.f};
    #pragma unroll
    for (int i = 0; i < 16; ++i) {
        floatx4 v = __builtin_nontemporal_load((const floatx4*)(base + ((size_t)i << 16)));
        rowacc += v;
        int row = i * 16 + c;
        int wg = (kq >> 1) ^ ((row ^ (row >> 4)) & 7);
        shortx4 h;
        h[0] = (short)f2bf(v[0]); h[1] = (short)f2bf(v[1]);
        h[2] = (short)f2bf(v[2]); h[3] = (short)f2bf(v[3]);
        *(shortx4*)(tbase + (size_t)row * 64 + wg * 8 + (kq & 1) * 4) = h;
        if (dt && c == i)
            *(floatx4*)&diagbuf[(size_t)(R + i) * 64 + kq * 4] = v;
        floatx4 cs = v;
        #pragma unroll
        for (int m = 16; m <= 32; m <<= 1) {
            cs[0] += __shfl_xor(cs[0], m);
            cs[1] += __shfl_xor(cs[1], m);
            cs[2] += __shfl_xor(cs[2], m);
            cs[3] += __shfl_xor(cs[3], m);
        }
        if (cl == 0) *(floatx4*)&colp[w][i][kq * 4] = cs;
    }
    *(floatx4*)&rowpart[(size_t)ti * 65536 + (size_t)(C + c) * 64 + kq * 4] = rowacc;
    __syncthreads();
    int i2 = t >> 4, kq2 = t & 15;
    floatx4 s = *(const floatx4*)&colp[0][i2][kq2 * 4];
    s += *(const floatx4*)&colp[1][i2][kq2 * 4];
    s += *(const floatx4*)&colp[2][i2][kq2 * 4];
    s += *(const floatx4*)&colp[3][i2][kq2 * 4];
    *(floatx4*)&colpart[(size_t)tj * 65536 + (size_t)(R + i2) * 64 + kq2 * 4] = s;
}

// =============== poolfin: fine-grained finisher, 536 blocks ===============
// b 0-255 rowfin (64 f4-slots each), 256-511 colfin+allraw, 512-519 diagsum,
// 520-535 wconv
__global__ __launch_bounds__(256) void poolfin_kernel(const float* __restrict__ rowpart,
        const float* __restrict__ colpart, const float* __restrict__ diagbuf,
        const float* __restrict__ wts,
        float* __restrict__ row_pool, float* __restrict__ col_pool,
        float* __restrict__ allraw, float* __restrict__ diagraw,
        unsigned short* __restrict__ w0t, unsigned short* __restrict__ w1t) {
    __shared__ floatx4 red[4][64];
    __shared__ floatx4 red2[4][16];
    int b = blockIdx.x, t = threadIdx.x;
    if (b < 256) {                          // rowfin
        int slot = b * 64 + (t & 63);
        int yq = t >> 6;
        const floatx4* rp4 = (const floatx4*)rowpart;
        floatx4 s = (floatx4){0.f, 0.f, 0.f, 0.f};
        #pragma unroll
        for (int y = 0; y < 16; ++y)
            s += rp4[(size_t)(yq * 16 + y) * 16384 + slot];
        red[yq][t & 63] = s;
        __syncthreads();
        if (t < 64) {
            floatx4 tot = red[0][t] + red[1][t] + red[2][t] + red[3][t];
            ((floatx4*)row_pool)[b * 64 + t] = tot * (1.f / 1024.f);
        }
    } else if (b < 512) {                   // colfin + allraw
        int bb = b - 256;
        int slot = bb * 64 + (t & 63);
        int yq = t >> 6;
        const floatx4* cp4 = (const floatx4*)colpart;
        floatx4 s = (floatx4){0.f, 0.f, 0.f, 0.f};
        #pragma unroll
        for (int y = 0; y < 16; ++y)
            s += cp4[(size_t)(yq * 16 + y) * 16384 + slot];
        red[yq][t & 63] = s;
        __syncthreads();
        if (t < 64) {
            floatx4 tot = red[0][t] + red[1][t] + red[2][t] + red[3][t];
            ((floatx4*)col_pool)[bb * 64 + t] = tot * (1.f / 1024.f);
            red2[t >> 4][t & 15] = tot;     // 4 r-rows x 16 kq
        }
        __syncthreads();
        if (t < 16) {
            floatx4 a = red2[0][t] + red2[1][t] + red2[2][t] + red2[3][t];
            atomicAdd(&allraw[t * 4 + 0], a[0]);
            atomicAdd(&allraw[t * 4 + 1], a[1]);
            atomicAdd(&allraw[t * 4 + 2], a[2]);
            atomicAdd(&allraw[t * 4 + 3], a[3]);
        }
    } else if (b < 520) {                   // diag sum (8 blocks x 128 rows)
        int d = b - 512;
        int k = t & 63, rl = t >> 6;
        float sd = 0.f;
        #pragma unroll 8
        for (int u = 0; u < 32; ++u)
            sd += diagbuf[(size_t)(d * 128 + rl + 4 * u) * 64 + k];
        ((float*)red)[rl * 64 + k] = sd;
        __syncthreads();
        if (t < 64) {
            float* rr = (float*)red;
            atomicAdd(&diagraw[t], rr[t] + rr[64 + t] + rr[128 + t] + rr[192 + t]);
        }
    } else {                                // wconv (16 blocks)
        int idx = (b - 520) * 256 + t;
        int n = idx >> 6, k = idx & 63;
        w0t[idx] = f2bf(wts[k * 64 + n]);
        w1t[idx] = f2bf(wts[4096 + k * 64 + n]);
    }
}

// =============== abd: 256 blocks x 4 rows (W L2-resident) ===============
__global__ __launch_bounds__(256) void abd_kernel(const float* __restrict__ W,
        const float* __restrict__ col_pool, const float* __restrict__ row_pool,
        const float* __restrict__ diagbuf, const float* __restrict__ allraw,
        const float* __restrict__ diagraw,
        float* __restrict__ Ab, float* __restrict__ Bb, float* __restrict__ Dgb) {
    __shared__ float rp[4][64], cp[4][64], dv[4][64], ap[64], dp[64];
    int t = threadIdx.x, o = t & 63, il = t >> 6;
    int i0 = blockIdx.x * 4;
    rp[il][o] = row_pool[(i0 + il) * 64 + o];
    cp[il][o] = col_pool[(i0 + il) * 64 + o];
    dv[il][o] = diagbuf[(i0 + il) * 64 + o];
    if (t < 64) {
        ap[t] = allraw[t] * (1.f / 1048576.f);
        dp[t] = diagraw[t] * (1.f / 1024.f);
    }
    __syncthreads();
    float aA = 0.f, aB = 0.f, aD = 0.f, cA = 0.f, cD = 0.f;
    #pragma unroll 4
    for (int k = 0; k < 64; ++k) {
        int ko = k * 64 + o;
        float rA = rp[il][k], cAk = cp[il][k], dA = dv[il][k];
        aA += rA * W[3 * 4096 + ko] + cAk * W[6 * 4096 + ko] + dA * W[13 * 4096 + ko];
        aB += rA * W[4 * 4096 + ko] + cAk * W[5 * 4096 + ko] + dA * W[14 * 4096 + ko];
        aD += dA * W[2 * 4096 + ko] + rA * W[10 * 4096 + ko] + cAk * W[11 * 4096 + ko];
        cA += ap[k] * W[7 * 4096 + ko] + dp[k] * W[12 * 4096 + ko];
        cD += dp[k] * W[8 * 4096 + ko] + ap[k] * W[9 * 4096 + ko];
    }
    Ab[(i0 + il) * 64 + o]  = aA + cA;
    Bb[(i0 + il) * 64 + o]  = aB;
    Dgb[(i0 + il) * 64 + o] = aD + cD;
}

// =============== main paired-tile kernel (R12-exact): 2080 blocks x 256 thr
__global__ __launch_bounds__(256, 2) void main_kernel(const unsigned short* __restrict__ bfcopy,
        const unsigned short* __restrict__ w0t, const unsigned short* __restrict__ w1t,
        const float* __restrict__ Ab, const float* __restrict__ Bb,
        const float* __restrict__ Dgb, float* __restrict__ out) {
    __shared__ short lds[32768];

    int t = threadIdx.x;
    int lane = t & 63, w = t >> 6;
    int lrow = lane & 15, lhi = lane >> 4;

    int p = blockIdx.x;
    float fb = (129.0f - sqrtf(129.0f * 129.0f - 8.0f * (float)p)) * 0.5f;
    int bi = (int)fb;
    while (bi > 0 && bi * (129 - bi) / 2 > p) --bi;
    while ((bi + 1) * (129 - (bi + 1)) / 2 <= p) ++bi;
    int bj = bi + (p - bi * (129 - bi) / 2);
    int r0 = bi * 16, c0 = bj * 16;
    bool diag = (bi == bj);

    const unsigned short* t0 = bfcopy + ((size_t)(bi * 64 + bj) << 14);
    const unsigned short* t1 = bfcopy + ((size_t)(bj * 64 + bi) << 14);
    #pragma unroll
    for (int n = 0; n < 8; ++n) {
        int g = n * 256 + t;
        GLOAD_LDS16(t0 + g * 8, lds + g * 8);
    }
    if (!diag) {
        #pragma unroll
        for (int n = 0; n < 8; ++n) {
            int g = n * 256 + t;
            GLOAD_LDS16(t1 + g * 8, lds + 16384 + g * 8);
        }
    }

    short8 bw0[2][4], bw1[2][4];
    #pragma unroll
    for (int kg = 0; kg < 2; ++kg)
        #pragma unroll
        for (int nt = 0; nt < 4; ++nt) {
            int off = (nt * 16 + lrow) * 64 + kg * 32 + lhi * 8;
            bw0[kg][nt] = *(const short8*)(w0t + off);
            bw1[kg][nt] = *(const short8*)(w1t + off);
        }
    float pA[2][4][4], pB[2][4][4];
    #pragma unroll
    for (int sel = 0; sel < 2; ++sel) {
        int rbase = sel ? c0 : r0;
        int cbase = sel ? r0 : c0;
        #pragma unroll
        for (int x = 0; x < 4; ++x)
            #pragma unroll
            for (int nt = 0; nt < 4; ++nt) {
                pA[sel][x][nt] = Ab[(cbase + lhi * 4 + x) * 64 + nt * 16 + lrow];
                pB[sel][x][nt] = Bb[(rbase + w * 4 + x) * 64 + nt * 16 + lrow];
            }
    }
    __syncthreads();

    int base1 = diag ? 0 : 16384;

    #pragma unroll
    for (int sel = 0; sel < 2; ++sel) {
        if (sel == 1 && diag) continue;
        int selb = sel ? base1 : 0;
        int othb = sel ? 0 : base1;
        int rbase = sel ? c0 : r0;
        int cbase = sel ? r0 : c0;
        #pragma unroll
        for (int mf = 0; mf < 4; ++mf) {
            int I = w * 4 + mf;
            int mrow = I * 16 + lrow;
            int swzm = (mrow ^ (mrow >> 4)) & 7;
            int trow = lrow * 16 + I;
            int swzt = (trow ^ (trow >> 4)) & 7;
            short8 ad[2], at2[2];
            #pragma unroll
            for (int kg = 0; kg < 2; ++kg) {
                ad[kg]  = *(const short8*)(lds + selb + mrow * 64 + ((kg * 4 + lhi) ^ swzm) * 8);
                at2[kg] = *(const short8*)(lds + othb + trow * 64 + ((kg * 4 + lhi) ^ swzt) * 8);
            }
            floatx4 acc[4];
            #pragma unroll
            for (int nt = 0; nt < 4; ++nt) acc[nt] = (floatx4){0.f, 0.f, 0.f, 0.f};
            #pragma unroll
            for (int nt = 0; nt < 4; ++nt) {
                acc[nt] = __builtin_amdgcn_mfma_f32_16x16x32_bf16(ad[0],  bw0[0][nt], acc[nt], 0, 0, 0);
                acc[nt] = __builtin_amdgcn_mfma_f32_16x16x32_bf16(ad[1],  bw0[1][nt], acc[nt], 0, 0, 0);
                acc[nt] = __builtin_amdgcn_mfma_f32_16x16x32_bf16(at2[0], bw1[0][nt], acc[nt], 0, 0, 0);
                acc[nt] = __builtin_amdgcn_mfma_f32_16x16x32_bf16(at2[1], bw1[1][nt], acc[nt], 0, 0, 0);
            }
            int ridx = rbase + I;
            #pragma unroll
            for (int jj = 0; jj < 4; ++jj) {
                int j = lhi * 4 + jj;
                int cidx = cbase + j;
                size_t s = ((size_t)ridx << 10) + cidx;
                bool isd = diag && (I == j);
                #pragma unroll
                for (int nt = 0; nt < 4; ++nt) {
                    float v = acc[nt][jj] + pA[sel][jj][nt] + pB[sel][mf][nt];
                    if (isd) v += Dgb[ridx * 64 + nt * 16 + lrow];
                    __builtin_nontemporal_store(v, &out[s * 64 + nt * 16 + lrow]);
                }
            }
        }
    }
}

extern "C" void kernel_launch(void* const* d_in, const int* in_sizes, int n_in,
                              void* d_out, int out_size, void* d_ws, size_t ws_size,
                              hipStream_t stream) {
    const float* in  = (const float*)d_in[0];
    const float* wts = (const float*)d_in[1];
    float* out = (float*)d_out;
    float* ws = (float*)d_ws;

    unsigned short* bfcopy = (unsigned short*)ws;       // 128 MB
    float* rowpart  = ws + 33554432;
    float* colpart  = ws + 37748736;
    float* row_pool = ws + 41943040;
    float* col_pool = ws + 42008576;
    float* diagbuf  = ws + 42074112;
    float* allraw   = ws + 42139648;
    float* diagraw  = ws + 42139712;
    float* Ab       = ws + 42139776;
    float* Bb       = ws + 42205312;
    float* Dgb      = ws + 42270848;
    unsigned short* w0t = (unsigned short*)(ws + 42336384);
    unsigned short* w1t = w0t + 4096;

    (void)hipMemsetAsync((void*)allraw, 0, 128 * sizeof(float), stream);

    sweep_kernel<<<dim3(64, 64), 256, 0, stream>>>(in, bfcopy, rowpart, colpart, diagbuf);
    poolfin_kernel<<<536, 256, 0, stream>>>(rowpart, colpart, diagbuf, wts,
                                            row_pool, col_pool, allraw, diagraw, w0t, w1t);
    abd_kernel<<<256, 256, 0, stream>>>(wts, col_pool, row_pool, diagbuf,
                                        allraw, diagraw, Ab, Bb, Dgb);
    main_kernel<<<2080, 256, 0, stream>>>(bfcopy, w0t, w1t, Ab, Bb, Dgb, out);
}

// Round 15
// 203.056 us; speedup vs baseline: 1.1764x; 1.0897x over previous
//
#include <hip/hip_runtime.h>
#include <hip/hip_bf16.h>

typedef __attribute__((ext_vector_type(4))) short shortx4;
typedef __attribute__((ext_vector_type(8))) short short8;
typedef __attribute__((ext_vector_type(4))) float floatx4;

__device__ __forceinline__ unsigned short f2bf(float f) {
    __hip_bfloat16 h = __float2bfloat16(f);
    return __builtin_bit_cast(unsigned short, h);
}

#define GLOAD_LDS16(g, l) __builtin_amdgcn_global_load_lds(                      \
    (const __attribute__((address_space(1))) void*)(g),                          \
    (__attribute__((address_space(3))) void*)(l), 16, 0, 0)

// =============== sweep (R12-exact): single NT read of input ===============
__global__ __launch_bounds__(256) void sweep_kernel(const float* __restrict__ in,
        unsigned short* __restrict__ bfcopy, float* __restrict__ rowpart,
        float* __restrict__ colpart, float* __restrict__ diagbuf) {
    __shared__ float colp[4][16][64];
    int t = threadIdx.x;
    int kq = t & 15;
    int cl = (t >> 4) & 3;
    int w  = t >> 6;
    int c  = w * 4 + cl;
    int ti = blockIdx.y, tj = blockIdx.x;
    int R = ti * 16, C = tj * 16;
    const float* base = in + ((size_t)R << 16) + (size_t)(C + c) * 64 + kq * 4;
    unsigned short* tbase = bfcopy + ((size_t)(ti * 64 + tj) << 14);
    bool dt = (ti == tj);

    floatx4 rowacc = (floatx4){0.f, 0.f, 0.f, 0.f};
    #pragma unroll
    for (int i = 0; i < 16; ++i) {
        floatx4 v = __builtin_nontemporal_load((const floatx4*)(base + ((size_t)i << 16)));
        rowacc += v;
        int row = i * 16 + c;
        int wg = (kq >> 1) ^ ((row ^ (row >> 4)) & 7);
        shortx4 h;
        h[0] = (short)f2bf(v[0]); h[1] = (short)f2bf(v[1]);
        h[2] = (short)f2bf(v[2]); h[3] = (short)f2bf(v[3]);
        *(shortx4*)(tbase + (size_t)row * 64 + wg * 8 + (kq & 1) * 4) = h;
        if (dt && c == i)
            *(floatx4*)&diagbuf[(size_t)(R + i) * 64 + kq * 4] = v;
        floatx4 cs = v;
        #pragma unroll
        for (int m = 16; m <= 32; m <<= 1) {
            cs[0] += __shfl_xor(cs[0], m);
            cs[1] += __shfl_xor(cs[1], m);
            cs[2] += __shfl_xor(cs[2], m);
            cs[3] += __shfl_xor(cs[3], m);
        }
        if (cl == 0) *(floatx4*)&colp[w][i][kq * 4] = cs;
    }
    *(floatx4*)&rowpart[(size_t)ti * 65536 + (size_t)(C + c) * 64 + kq * 4] = rowacc;
    __syncthreads();
    int i2 = t >> 4, kq2 = t & 15;
    floatx4 s = *(const floatx4*)&colp[0][i2][kq2 * 4];
    s += *(const floatx4*)&colp[1][i2][kq2 * 4];
    s += *(const floatx4*)&colp[2][i2][kq2 * 4];
    s += *(const floatx4*)&colp[3][i2][kq2 * 4];
    *(floatx4*)&colpart[(size_t)tj * 65536 + (size_t)(R + i2) * 64 + kq2 * 4] = s;
}

// =============== finred: allraw (from rowpart) + diagraw + wconv, 88 blocks
__global__ __launch_bounds__(256) void finred_kernel(const float* __restrict__ rowpart,
        const float* __restrict__ diagbuf, const float* __restrict__ wts,
        float* __restrict__ allraw, float* __restrict__ diagraw,
        unsigned short* __restrict__ w0t, unsigned short* __restrict__ w1t) {
    __shared__ float red[4][64];
    int b = blockIdx.x, t = threadIdx.x;
    if (b < 64) {                           // allraw: c-slice [b*16, b*16+16)
        int o = t & 63, seg = t >> 6;
        float s = 0.f;
        #pragma unroll 4
        for (int y = 0; y < 16; ++y)
            #pragma unroll
            for (int cl = 0; cl < 4; ++cl) {
                int c = b * 16 + seg * 4 + cl;
                s += rowpart[(size_t)y * 65536 + (size_t)c * 64 + o];
            }
        red[seg][o] = s;
        __syncthreads();
        if (t < 64)
            atomicAdd(&allraw[t], red[0][t] + red[1][t] + red[2][t] + red[3][t]);
    } else if (b < 72) {                    // diagraw (8 blocks x 128 rows)
        int d = b - 64;
        int k = t & 63, rl = t >> 6;
        float sd = 0.f;
        #pragma unroll 8
        for (int u = 0; u < 32; ++u)
            sd += diagbuf[(size_t)(d * 128 + rl + 4 * u) * 64 + k];
        red[rl][k] = sd;
        __syncthreads();
        if (t < 64)
            atomicAdd(&diagraw[t], red[0][t] + red[1][t] + red[2][t] + red[3][t]);
    } else {                                // wconv (16 blocks)
        int idx = (b - 72) * 256 + t;
        int n = idx >> 6, k = idx & 63;
        w0t[idx] = f2bf(wts[k * 64 + n]);
        w1t[idx] = f2bf(wts[4096 + k * 64 + n]);
    }
}

// =============== abd2: 256 blocks x 4 rows, self-reduces pools from partials
__global__ __launch_bounds__(256) void abd_kernel(const float* __restrict__ W,
        const float* __restrict__ rowpart, const float* __restrict__ colpart,
        const float* __restrict__ diagbuf, const float* __restrict__ allraw,
        const float* __restrict__ diagraw,
        float* __restrict__ Ab, float* __restrict__ Bb, float* __restrict__ Dgb) {
    __shared__ float rp[4][64], cp[4][64], dv[4][64], ap[64], dp[64];
    int t = threadIdx.x, o = t & 63, il = t >> 6;
    int i0 = blockIdx.x * 4;
    int i = i0 + il;
    float sr = 0.f;
    #pragma unroll 4
    for (int y = 0; y < 16; ++y)
        sr += rowpart[(size_t)y * 65536 + (size_t)i * 64 + o];
    rp[il][o] = sr * (1.f / 1024.f);
    float sc = 0.f;
    #pragma unroll 8
    for (int y = 0; y < 64; ++y)
        sc += colpart[(size_t)y * 65536 + (size_t)i * 64 + o];
    cp[il][o] = sc * (1.f / 1024.f);
    dv[il][o] = diagbuf[i * 64 + o];
    if (t < 64) {
        ap[t] = allraw[t] * (1.f / 1048576.f);
        dp[t] = diagraw[t] * (1.f / 1024.f);
    }
    __syncthreads();
    float aA = 0.f, aB = 0.f, aD = 0.f, cA = 0.f, cD = 0.f;
    #pragma unroll 4
    for (int k = 0; k < 64; ++k) {
        int ko = k * 64 + o;
        float rA = rp[il][k], cAk = cp[il][k], dA = dv[il][k];
        aA += rA * W[3 * 4096 + ko] + cAk * W[6 * 4096 + ko] + dA * W[13 * 4096 + ko];
        aB += rA * W[4 * 4096 + ko] + cAk * W[5 * 4096 + ko] + dA * W[14 * 4096 + ko];
        aD += dA * W[2 * 4096 + ko] + rA * W[10 * 4096 + ko] + cAk * W[11 * 4096 + ko];
        cA += ap[k] * W[7 * 4096 + ko] + dp[k] * W[12 * 4096 + ko];
        cD += dp[k] * W[8 * 4096 + ko] + ap[k] * W[9 * 4096 + ko];
    }
    Ab[i * 64 + o]  = aA + cA;
    Bb[i * 64 + o]  = aB;
    Dgb[i * 64 + o] = aD + cD;
}

// =============== main (R12-exact): 2080 blocks x 256 thr ===============
__global__ __launch_bounds__(256, 2) void main_kernel(const unsigned short* __restrict__ bfcopy,
        const unsigned short* __restrict__ w0t, const unsigned short* __restrict__ w1t,
        const float* __restrict__ Ab, const float* __restrict__ Bb,
        const float* __restrict__ Dgb, float* __restrict__ out) {
    __shared__ short lds[32768];

    int t = threadIdx.x;
    int lane = t & 63, w = t >> 6;
    int lrow = lane & 15, lhi = lane >> 4;

    int p = blockIdx.x;
    float fb = (129.0f - sqrtf(129.0f * 129.0f - 8.0f * (float)p)) * 0.5f;
    int bi = (int)fb;
    while (bi > 0 && bi * (129 - bi) / 2 > p) --bi;
    while ((bi + 1) * (129 - (bi + 1)) / 2 <= p) ++bi;
    int bj = bi + (p - bi * (129 - bi) / 2);
    int r0 = bi * 16, c0 = bj * 16;
    bool diag = (bi == bj);

    const unsigned short* t0 = bfcopy + ((size_t)(bi * 64 + bj) << 14);
    const unsigned short* t1 = bfcopy + ((size_t)(bj * 64 + bi) << 14);
    #pragma unroll
    for (int n = 0; n < 8; ++n) {
        int g = n * 256 + t;
        GLOAD_LDS16(t0 + g * 8, lds + g * 8);
    }
    if (!diag) {
        #pragma unroll
        for (int n = 0; n < 8; ++n) {
            int g = n * 256 + t;
            GLOAD_LDS16(t1 + g * 8, lds + 16384 + g * 8);
        }
    }

    short8 bw0[2][4], bw1[2][4];
    #pragma unroll
    for (int kg = 0; kg < 2; ++kg)
        #pragma unroll
        for (int nt = 0; nt < 4; ++nt) {
            int off = (nt * 16 + lrow) * 64 + kg * 32 + lhi * 8;
            bw0[kg][nt] = *(const short8*)(w0t + off);
            bw1[kg][nt] = *(const short8*)(w1t + off);
        }
    float pA[2][4][4], pB[2][4][4];
    #pragma unroll
    for (int sel = 0; sel < 2; ++sel) {
        int rbase = sel ? c0 : r0;
        int cbase = sel ? r0 : c0;
        #pragma unroll
        for (int x = 0; x < 4; ++x)
            #pragma unroll
            for (int nt = 0; nt < 4; ++nt) {
                pA[sel][x][nt] = Ab[(cbase + lhi * 4 + x) * 64 + nt * 16 + lrow];
                pB[sel][x][nt] = Bb[(rbase + w * 4 + x) * 64 + nt * 16 + lrow];
            }
    }
    __syncthreads();

    int base1 = diag ? 0 : 16384;

    #pragma unroll
    for (int sel = 0; sel < 2; ++sel) {
        if (sel == 1 && diag) continue;
        int selb = sel ? base1 : 0;
        int othb = sel ? 0 : base1;
        int rbase = sel ? c0 : r0;
        int cbase = sel ? r0 : c0;
        #pragma unroll
        for (int mf = 0; mf < 4; ++mf) {
            int I = w * 4 + mf;
            int mrow = I * 16 + lrow;
            int swzm = (mrow ^ (mrow >> 4)) & 7;
            int trow = lrow * 16 + I;
            int swzt = (trow ^ (trow >> 4)) & 7;
            short8 ad[2], at2[2];
            #pragma unroll
            for (int kg = 0; kg < 2; ++kg) {
                ad[kg]  = *(const short8*)(lds + selb + mrow * 64 + ((kg * 4 + lhi) ^ swzm) * 8);
                at2[kg] = *(const short8*)(lds + othb + trow * 64 + ((kg * 4 + lhi) ^ swzt) * 8);
            }
            floatx4 acc[4];
            #pragma unroll
            for (int nt = 0; nt < 4; ++nt) acc[nt] = (floatx4){0.f, 0.f, 0.f, 0.f};
            #pragma unroll
            for (int nt = 0; nt < 4; ++nt) {
                acc[nt] = __builtin_amdgcn_mfma_f32_16x16x32_bf16(ad[0],  bw0[0][nt], acc[nt], 0, 0, 0);
                acc[nt] = __builtin_amdgcn_mfma_f32_16x16x32_bf16(ad[1],  bw0[1][nt], acc[nt], 0, 0, 0);
                acc[nt] = __builtin_amdgcn_mfma_f32_16x16x32_bf16(at2[0], bw1[0][nt], acc[nt], 0, 0, 0);
                acc[nt] = __builtin_amdgcn_mfma_f32_16x16x32_bf16(at2[1], bw1[1][nt], acc[nt], 0, 0, 0);
            }
            int ridx = rbase + I;
            #pragma unroll
            for (int jj = 0; jj < 4; ++jj) {
                int j = lhi * 4 + jj;
                int cidx = cbase + j;
                size_t s = ((size_t)ridx << 10) + cidx;
                bool isd = diag && (I == j);
                #pragma unroll
                for (int nt = 0; nt < 4; ++nt) {
                    float v = acc[nt][jj] + pA[sel][jj][nt] + pB[sel][mf][nt];
                    if (isd) v += Dgb[ridx * 64 + nt * 16 + lrow];
                    __builtin_nontemporal_store(v, &out[s * 64 + nt * 16 + lrow]);
                }
            }
        }
    }
}

extern "C" void kernel_launch(void* const* d_in, const int* in_sizes, int n_in,
                              void* d_out, int out_size, void* d_ws, size_t ws_size,
                              hipStream_t stream) {
    const float* in  = (const float*)d_in[0];
    const float* wts = (const float*)d_in[1];
    float* out = (float*)d_out;
    float* ws = (float*)d_ws;

    unsigned short* bfcopy = (unsigned short*)ws;       // 128 MB
    float* rowpart  = ws + 33554432;         // 16*65536
    float* colpart  = ws + 37748736;         // 64*65536
    float* diagbuf  = ws + 42074112;
    float* allraw   = ws + 42139648;
    float* diagraw  = ws + 42139712;
    float* Ab       = ws + 42139776;
    float* Bb       = ws + 42205312;
    float* Dgb      = ws + 42270848;
    unsigned short* w0t = (unsigned short*)(ws + 42336384);
    unsigned short* w1t = w0t + 4096;

    (void)hipMemsetAsync((void*)allraw, 0, 128 * sizeof(float), stream);

    sweep_kernel<<<dim3(64, 64), 256, 0, stream>>>(in, bfcopy, rowpart, colpart, diagbuf);
    finred_kernel<<<88, 256, 0, stream>>>(rowpart, diagbuf, wts, allraw, diagraw, w0t, w1t);
    abd_kernel<<<256, 256, 0, stream>>>(wts, rowpart, colpart, diagbuf,
                                        allraw, diagraw, Ab, Bb, Dgb);
    main_kernel<<<2080, 256, 0, stream>>>(bfcopy, w0t, w1t, Ab, Bb, Dgb, out);
}